// Round 4
// baseline (200.965 us; speedup 1.0000x reference)
//
#include <hip/hip_runtime.h>
#include <stdint.h>

#define D_MODEL 1024
#define NHEADS  16
#define DHEAD   64
#define BATCH   4
#define SEQ     2048
#define MTOT    (BATCH*SEQ)

typedef unsigned short u16;
typedef uint32_t u32;
typedef __bf16 bf16x8 __attribute__((ext_vector_type(8)));
typedef float  f32x4  __attribute__((ext_vector_type(4)));
typedef float  f32x16 __attribute__((ext_vector_type(16)));
typedef u16    u16x8  __attribute__((ext_vector_type(8)));
typedef u16    u16x4  __attribute__((ext_vector_type(4)));
typedef u32    u32x4  __attribute__((ext_vector_type(4)));

__device__ __forceinline__ u16 f2bf(float f) {
  uint32_t u = __builtin_bit_cast(uint32_t, f);
  u += 0x7fff + ((u >> 16) & 1);   // RNE
  return (u16)(u >> 16);
}

__device__ __forceinline__ void gll16(const u16* g, u16* lds) {
  __builtin_amdgcn_global_load_lds(
      (__attribute__((address_space(1))) void*)(g),
      (__attribute__((address_space(3))) void*)(lds), 16, 0, 0);
}

// fp32 -> bf16 elementwise
__global__ void cvtk(const float4* __restrict__ in, u16x4* __restrict__ out, int n4) {
  const int i = blockIdx.x * blockDim.x + threadIdx.x;
  if (i < n4) {
    const float4 f = in[i];
    u16x4 h;
    h[0] = f2bf(f.x); h[1] = f2bf(f.y); h[2] = f2bf(f.z); h[3] = f2bf(f.w);
    out[i] = h;
  }
}

// 4 weight matrices in one launch (blockIdx.y selects source; outputs contiguous)
__global__ void cvtk4(const float4* __restrict__ a, const float4* __restrict__ b,
                      const float4* __restrict__ c, const float4* __restrict__ d,
                      u16x4* __restrict__ out, int n4) {
  const int i = blockIdx.x * blockDim.x + threadIdx.x;
  if (i >= n4) return;
  const float4* src = (blockIdx.y == 0) ? a : (blockIdx.y == 1) ? b
                    : (blockIdx.y == 2) ? c : d;
  const float4 f = src[i];
  u16x4 h;
  h[0] = f2bf(f.x); h[1] = f2bf(f.y); h[2] = f2bf(f.z); h[3] = f2bf(f.w);
  out[(size_t)blockIdx.y * n4 + i] = h;
}

// C = A (MxK, bf16) * B^T (B stored [N][K], bf16)
// MODE 0: fp32 store to Cout[M][D_MODEL]
// MODE 1: QKV: grid.z selects W; bf16 store permuted to [z][B][H][S][DHEAD]; z==0 scaled 0.125*log2e
template<int MODE>
__launch_bounds__(256)
__global__ void gemm_bt_k(const u16* __restrict__ A,
                          const u16* __restrict__ W0,
                          const u16* __restrict__ W1,
                          const u16* __restrict__ W2,
                          void* __restrict__ Cout)
{
  constexpr int K = D_MODEL;
  const int tid = threadIdx.x;
  const int l = tid & 63, w = tid >> 6;
  const int m0 = blockIdx.x * 128;
  const int n0 = blockIdx.y * 128;
  const u16* Bm = W0;
  float scale = 1.0f;
  if (MODE == 1) {
    const int z = blockIdx.z;
    Bm = (z == 0) ? W0 : ((z == 1) ? W1 : W2);
    scale = (z == 0) ? 0.125f * 1.44269504088896f : 1.0f;
  }

  __shared__ __align__(16) u16 As[128*32];
  __shared__ __align__(16) u16 Bs[128*32];

  f32x4 acc[4][4];
  #pragma unroll
  for (int i = 0; i < 4; ++i)
    #pragma unroll
    for (int j = 0; j < 4; ++j)
      acc[i][j] = f32x4{0.f, 0.f, 0.f, 0.f};

  const int wr = w >> 1, wc = w & 1;
  const int srow = l >> 2;
  const int scol = (l & 3) * 8;

  for (int k0 = 0; k0 < K; k0 += 32) {
    __syncthreads();
    #pragma unroll
    for (int j = 0; j < 2; ++j) {
      const int seg = w * 2 + j;
      gll16(A  + (size_t)(m0 + seg*16 + srow) * K + k0 + scol, &As[seg*512]);
      gll16(Bm + (size_t)(n0 + seg*16 + srow) * K + k0 + scol, &Bs[seg*512]);
    }
    __syncthreads();
    bf16x8 af[4], bfr[4];
    #pragma unroll
    for (int m = 0; m < 4; ++m)
      af[m] = *(const bf16x8*)&As[(wr*64 + m*16 + (l & 15))*32 + (l >> 4)*8];
    #pragma unroll
    for (int n = 0; n < 4; ++n)
      bfr[n] = *(const bf16x8*)&Bs[(wc*64 + n*16 + (l & 15))*32 + (l >> 4)*8];
    #pragma unroll
    for (int m = 0; m < 4; ++m)
      #pragma unroll
      for (int n = 0; n < 4; ++n)
        acc[m][n] = __builtin_amdgcn_mfma_f32_16x16x32_bf16(af[m], bfr[n], acc[m][n], 0, 0, 0);
  }

  const int g = l >> 4, c15 = l & 15;
  #pragma unroll
  for (int m = 0; m < 4; ++m) {
    #pragma unroll
    for (int n = 0; n < 4; ++n) {
      #pragma unroll
      for (int j = 0; j < 4; ++j) {
        const int row = m0 + wr*64 + m*16 + g*4 + j;
        const int col = n0 + wc*64 + n*16 + c15;
        const float v = acc[m][n][j] * scale;
        if (MODE == 0) {
          ((float*)Cout)[(size_t)row * D_MODEL + col] = v;
        } else {
          const int b = row >> 11, s = row & (SEQ-1);
          const int h = col >> 6, dh = col & (DHEAD-1);
          ((u16*)Cout)[(size_t)blockIdx.z * MTOT * D_MODEL
                       + ((size_t)(b*NHEADS + h) * SEQ + s) * DHEAD + dh] = f2bf(v);
        }
      }
    }
  }
}

// ---------------------------------------------------------------------------
// Causal flash attention, 4 warps x 32 q-rows (128-row superblock), 32x32x16
// MFMA, O^T form, 2 blocks/CU.
// grid = 512: block r -> bh = 8*(r&7)+((r>>3)&7) (XCD-pinned), pairi = r>>6;
// halves tq in {pairi, 15-pairi} -> constant 36 kv-tiles per block.
// Per kv-tile: S^T = mfma(K, Q^T) -> lane-local softmax (q = lane&31, T13
// defer-max) -> P^T B-frags via cvt_pk + permlane32_swap -> O^T += mfma(V^T,P^T).
// K via global_load_lds w/ pre-swizzled source; V^T scatter-staged as paired-row
// u32 writes. Chunk swizzle S(r) = (r&7)^(r>>3) on both. Epilogue via LDS.
// ---------------------------------------------------------------------------
__launch_bounds__(256)
__global__ void attn4_k(const u16* __restrict__ Qb, const u16* __restrict__ Kb_,
                        const u16* __restrict__ Vb_, u16* __restrict__ Oa)
{
  const int tid = threadIdx.x;
  const int w = tid >> 6, l = tid & 63;
  const int q5 = l & 31, hi = l >> 5;
  const int r = blockIdx.x;
  const int bh = (r & 7) * 8 + ((r >> 3) & 7);
  const int pairi = r >> 6;                     // 0..7
  const int b = bh >> 4, h = bh & 15;
  const size_t base = (size_t)bh * SEQ * DHEAD;
  const u16* Qg = Qb + base;
  const u16* Kg = Kb_ + base;
  const u16* Vg = Vb_ + base;

  // 32KB: K bufs [2][4096] u16 | V bufs at u16-ofs 8192 [2][4096]; epilogue Ot[4][2048]
  __shared__ __align__(16) u16 smem[16384];

  // V staging: thread handles rows {2rp, 2rp+1}, d-chunk kc (8 u32 writes/tile)
  const int kc = tid & 7, rp = tid >> 3;        // rp 0..31
  int vIdx32[8];
  #pragma unroll
  for (int e = 0; e < 8; ++e) {
    const int d = 8*kc + e;
    vIdx32[e] = d*32 + ((((rp >> 2) ^ kc ^ e) & 7) << 2) + (rp & 3);
  }
  // K staging: wave w, call j: rows 16w+8j+(l>>3); pre-swizzled source chunk
  const int krow = l >> 3, ksl = l & 7;

  for (int half = 0; half < 2; ++half) {
    const int tq = half ? (15 - pairi) : pairi;
    const int q0w = tq*128 + 32*w;
    const int ntk = 2*tq + 2;                   // block kv-tiles
    const int ntw = 2*tq + (w >> 1) + 1;        // this warp's compute tiles

    bf16x8 qf[4];
    #pragma unroll
    for (int s = 0; s < 4; ++s)
      qf[s] = *(const bf16x8*)(Qg + (size_t)(q0w + q5)*DHEAD + 16*s + 8*hi);

    f32x16 c0 = {}, c1 = {};                    // O^T accum (cols q = lane&31)
    float mrun = -1e30f, lrun = 0.f;

    // prologue: stage tile 0 -> buf 0
    {
      #pragma unroll
      for (int j = 0; j < 2; ++j)
        gll16(Kg + (size_t)(16*w + 8*j + krow)*DHEAD + (size_t)((ksl ^ krow ^ (2*w + j)) & 7)*8,
              smem + (w*128 + j*64)*8);
      const u16x8 v0 = *(const u16x8*)(Vg + (size_t)(2*rp)*DHEAD + kc*8);
      const u16x8 v1 = *(const u16x8*)(Vg + (size_t)(2*rp + 1)*DHEAD + kc*8);
      u32* Vd = (u32*)(smem + 8192);
      #pragma unroll
      for (int e = 0; e < 8; ++e)
        Vd[vIdx32[e]] = (u32)v0[e] | ((u32)v1[e] << 16);
    }
    __syncthreads();

    for (int t = 0; t < ntk; ++t) {
      const int cur = t & 1;
      const bool pf = (t + 1 < ntk);
      u16x8 v0, v1;
      if (pf) {
        const int kv1 = (t + 1)*64;
        v0 = *(const u16x8*)(Vg + (size_t)(kv1 + 2*rp)*DHEAD + kc*8);
        v1 = *(const u16x8*)(Vg + (size_t)(kv1 + 2*rp + 1)*DHEAD + kc*8);
        #pragma unroll
        for (int j = 0; j < 2; ++j)
          gll16(Kg + (size_t)(kv1 + 16*w + 8*j + krow)*DHEAD + (size_t)((ksl ^ krow ^ (2*w + j)) & 7)*8,
                smem + ((cur^1)*512 + w*128 + j*64)*8);
      }

      if (t < ntw) {
        const u16* Kb = smem + cur*4096;
        const u16* Vv = smem + 8192 + cur*4096;

        // ---- S^T = K * Q^T ----
        f32x16 st[2] = {{}, {}};
        __builtin_amdgcn_s_setprio(1);
        #pragma unroll
        for (int kb = 0; kb < 2; ++kb) {
          #pragma unroll
          for (int s = 0; s < 4; ++s) {
            const int slot = ((2*s + hi) ^ (l & 7) ^ (4*kb) ^ (q5 >> 3)) & 7;
            const bf16x8 kf = *(const bf16x8*)(Kb + (32*kb + q5)*64 + slot*8);
            st[kb] = __builtin_amdgcn_mfma_f32_32x32x16_bf16(kf, qf[s], st[kb], 0, 0, 0);
          }
        }
        __builtin_amdgcn_s_setprio(0);

        // ---- causal mask (warp's diagonal tile only) ----
        if (t == ntw - 1) {
          const int kv0 = t*64;
          #pragma unroll
          for (int kb = 0; kb < 2; ++kb)
            #pragma unroll
            for (int rr = 0; rr < 16; ++rr) {
              const int kvg = kv0 + 32*kb + (rr & 3) + 8*(rr >> 2) + 4*hi;
              if (kvg > q0w + q5) st[kb][rr] = -1e30f;
            }
        }

        // ---- lane-local online softmax w/ defer-max (q-row = q5; partner l^32) ----
        float mx = -1e30f;
        #pragma unroll
        for (int kb = 0; kb < 2; ++kb)
          #pragma unroll
          for (int rr = 0; rr < 16; ++rr) mx = fmaxf(mx, st[kb][rr]);
        mx = fmaxf(mx, __shfl_xor(mx, 32));
        float alpha = 1.0f;
        if (!__all(mx <= mrun + 8.0f)) {
          const float mnew = fmaxf(mrun, mx);
          alpha = __builtin_amdgcn_exp2f(mrun - mnew);
          mrun = mnew;
          #pragma unroll
          for (int rr = 0; rr < 16; ++rr) { c0[rr] *= alpha; c1[rr] *= alpha; }
        }
        float rs = 0.f;
        #pragma unroll
        for (int kb = 0; kb < 2; ++kb)
          #pragma unroll
          for (int rr = 0; rr < 16; ++rr) {
            const float p = __builtin_amdgcn_exp2f(st[kb][rr] - mrun);
            st[kb][rr] = p;
            rs += p;
          }
        rs += __shfl_xor(rs, 32);
        lrun = lrun * alpha + rs;

        // ---- P^T -> B-frags: 16 cvt_pk + 8 permlane32_swap ----
        bf16x8 pb[4];
        #pragma unroll
        for (int kb = 0; kb < 2; ++kb) {
          u32 pw[8];
          #pragma unroll
          for (int i = 0; i < 8; ++i) {
            u32 t0;
            asm("v_cvt_pk_bf16_f32 %0, %1, %2"
                : "=v"(t0) : "v"(st[kb][2*i]), "v"(st[kb][2*i+1]));
            pw[i] = t0;
          }
          asm("v_permlane32_swap_b32 %0, %1" : "+v"(pw[0]), "+v"(pw[2]));
          asm("v_permlane32_swap_b32 %0, %1" : "+v"(pw[1]), "+v"(pw[3]));
          asm("v_permlane32_swap_b32 %0, %1" : "+v"(pw[4]), "+v"(pw[6]));
          asm("v_permlane32_swap_b32 %0, %1" : "+v"(pw[5]), "+v"(pw[7]));
          pb[2*kb]   = __builtin_bit_cast(bf16x8, u32x4{pw[0], pw[1], pw[2], pw[3]});
          pb[2*kb+1] = __builtin_bit_cast(bf16x8, u32x4{pw[4], pw[5], pw[6], pw[7]});
        }

        // ---- O^T += V^T * P^T ----
        __builtin_amdgcn_s_setprio(1);
        #pragma unroll
        for (int s = 0; s < 4; ++s) {
          {
            const int slot = ((2*s + hi) ^ (l & 7) ^ (q5 >> 3)) & 7;
            const bf16x8 vf = *(const bf16x8*)(Vv + q5*64 + slot*8);
            c0 = __builtin_amdgcn_mfma_f32_32x32x16_bf16(vf, pb[s], c0, 0, 0, 0);
          }
          {
            const int slot = ((2*s + hi) ^ (l & 7) ^ 4 ^ (q5 >> 3)) & 7;
            const bf16x8 vf = *(const bf16x8*)(Vv + (32 + q5)*64 + slot*8);
            c1 = __builtin_amdgcn_mfma_f32_32x32x16_bf16(vf, pb[s], c1, 0, 0, 0);
          }
        }
        __builtin_amdgcn_s_setprio(0);
      }

      if (pf) {
        u32* Vd = (u32*)(smem + 8192) + (cur^1)*2048;
        #pragma unroll
        for (int e = 0; e < 8; ++e)
          Vd[vIdx32[e]] = (u32)v0[e] | ((u32)v1[e] << 16);
      }
      __syncthreads();
    }

    // ---- epilogue: normalize (lane-local), transpose via LDS, store ----
    const float linv = __builtin_amdgcn_rcpf(lrun);
    #pragma unroll
    for (int Ab = 0; Ab < 2; ++Ab)
      #pragma unroll
      for (int rr = 0; rr < 16; ++rr) {
        const int d = 32*Ab + (rr & 3) + 8*(rr >> 2) + 4*hi;
        smem[w*2048 + q5*64 + (((d >> 3) ^ (q5 & 7)) & 7)*8 + (d & 7)] =
            f2bf((Ab ? c1[rr] : c0[rr]) * linv);
      }
    __syncthreads();
    #pragma unroll
    for (int cc = 0; cc < 4; ++cc) {
      const int dchunk = 4*hi + cc;
      const u16x8 vv = *(const u16x8*)&smem[w*2048 + q5*64 + ((dchunk ^ (q5 & 7)) & 7)*8];
      *(u16x8*)(Oa + (size_t)(b*SEQ + q0w + q5)*D_MODEL + h*DHEAD + 32*hi + 8*cc) = vv;
    }
    __syncthreads();
  }
}

extern "C" void kernel_launch(void* const* d_in, const int* in_sizes, int n_in,
                              void* d_out, int out_size, void* d_ws, size_t ws_size,
                              hipStream_t stream) {
  const float* X  = (const float*)d_in[0];
  const float* Wq = (const float*)d_in[1];
  const float* Wk = (const float*)d_in[2];
  const float* Wv = (const float*)d_in[3];
  const float* Wo = (const float*)d_in[4];

  u16* xb  = (u16*)d_ws;
  u16* wqb = xb  + (size_t)MTOT*D_MODEL;
  u16* wkb = wqb + (size_t)D_MODEL*D_MODEL;
  u16* wvb = wkb + (size_t)D_MODEL*D_MODEL;
  u16* wob = wvb + (size_t)D_MODEL*D_MODEL;
  u16* qkv = wob + (size_t)D_MODEL*D_MODEL;   // [3][B*H][S][64]
  u16* att = qkv + (size_t)3*MTOT*D_MODEL;    // [8192][1024]

  const int nx4 = MTOT*D_MODEL/4;
  const int nw4 = D_MODEL*D_MODEL/4;
  cvtk<<<nx4/256, 256, 0, stream>>>((const float4*)X, (u16x4*)xb, nx4);
  dim3 gc(nw4/256, 4, 1);
  cvtk4<<<gc, 256, 0, stream>>>((const float4*)Wq, (const float4*)Wk,
                                (const float4*)Wv, (const float4*)Wo,
                                (u16x4*)wqb, nw4);

  dim3 g1(MTOT/128, D_MODEL/128, 3);
  gemm_bt_k<1><<<g1, 256, 0, stream>>>(xb, wqb, wkb, wvb, (void*)qkv);

  attn4_k<<<512, 256, 0, stream>>>(qkv, qkv + (size_t)MTOT*D_MODEL,
                                   qkv + (size_t)2*MTOT*D_MODEL, att);

  dim3 g3(MTOT/128, D_MODEL/128, 1);
  gemm_bt_k<0><<<g3, 256, 0, stream>>>(att, wob, nullptr, nullptr, d_out);
}

// Round 5
// 178.467 us; speedup vs baseline: 1.1261x; 1.1261x over previous
//
#include <hip/hip_runtime.h>
#include <stdint.h>

#define D_MODEL 1024
#define NHEADS  16
#define DHEAD   64
#define BATCH   4
#define SEQ     2048
#define MTOT    (BATCH*SEQ)

typedef unsigned short u16;
typedef uint32_t u32;
typedef __bf16 bf16x8 __attribute__((ext_vector_type(8)));
typedef float  f32x4  __attribute__((ext_vector_type(4)));
typedef float  f32x16 __attribute__((ext_vector_type(16)));
typedef u16    u16x8  __attribute__((ext_vector_type(8)));
typedef u16    u16x4  __attribute__((ext_vector_type(4)));
typedef u32    u32x4  __attribute__((ext_vector_type(4)));

__device__ __forceinline__ u16 f2bf(float f) {
  uint32_t u = __builtin_bit_cast(uint32_t, f);
  u += 0x7fff + ((u >> 16) & 1);   // RNE
  return (u16)(u >> 16);
}

__device__ __forceinline__ void gll16(const u16* g, u16* lds) {
  __builtin_amdgcn_global_load_lds(
      (__attribute__((address_space(1))) void*)(g),
      (__attribute__((address_space(3))) void*)(lds), 16, 0, 0);
}

// fp32 -> bf16 elementwise
__global__ void cvtk(const float4* __restrict__ in, u16x4* __restrict__ out, int n4) {
  const int i = blockIdx.x * blockDim.x + threadIdx.x;
  if (i < n4) {
    const float4 f = in[i];
    u16x4 h;
    h[0] = f2bf(f.x); h[1] = f2bf(f.y); h[2] = f2bf(f.z); h[3] = f2bf(f.w);
    out[i] = h;
  }
}

// 4 weight matrices in one launch (blockIdx.y selects source; outputs contiguous)
__global__ void cvtk4(const float4* __restrict__ a, const float4* __restrict__ b,
                      const float4* __restrict__ c, const float4* __restrict__ d,
                      u16x4* __restrict__ out, int n4) {
  const int i = blockIdx.x * blockDim.x + threadIdx.x;
  if (i >= n4) return;
  const float4* src = (blockIdx.y == 0) ? a : (blockIdx.y == 1) ? b
                    : (blockIdx.y == 2) ? c : d;
  const float4 f = src[i];
  u16x4 h;
  h[0] = f2bf(f.x); h[1] = f2bf(f.y); h[2] = f2bf(f.z); h[3] = f2bf(f.w);
  out[(size_t)blockIdx.y * n4 + i] = h;
}

// C = A (MxK, bf16) * B^T (B stored [N][K], bf16)
// MODE 0: fp32 store to Cout[M][D_MODEL]
// MODE 1: QKV: grid.z selects W; bf16 store permuted to [z][B][H][S][DHEAD]; z==0 scaled 0.125*log2e
template<int MODE>
__launch_bounds__(256)
__global__ void gemm_bt_k(const u16* __restrict__ A,
                          const u16* __restrict__ W0,
                          const u16* __restrict__ W1,
                          const u16* __restrict__ W2,
                          void* __restrict__ Cout)
{
  constexpr int K = D_MODEL;
  const int tid = threadIdx.x;
  const int l = tid & 63, w = tid >> 6;
  const int m0 = blockIdx.x * 128;
  const int n0 = blockIdx.y * 128;
  const u16* Bm = W0;
  float scale = 1.0f;
  if (MODE == 1) {
    const int z = blockIdx.z;
    Bm = (z == 0) ? W0 : ((z == 1) ? W1 : W2);
    scale = (z == 0) ? 0.125f * 1.44269504088896f : 1.0f;
  }

  __shared__ __align__(16) u16 As[128*32];
  __shared__ __align__(16) u16 Bs[128*32];

  f32x4 acc[4][4];
  #pragma unroll
  for (int i = 0; i < 4; ++i)
    #pragma unroll
    for (int j = 0; j < 4; ++j)
      acc[i][j] = f32x4{0.f, 0.f, 0.f, 0.f};

  const int wr = w >> 1, wc = w & 1;
  const int srow = l >> 2;
  const int scol = (l & 3) * 8;

  for (int k0 = 0; k0 < K; k0 += 32) {
    __syncthreads();
    #pragma unroll
    for (int j = 0; j < 2; ++j) {
      const int seg = w * 2 + j;
      gll16(A  + (size_t)(m0 + seg*16 + srow) * K + k0 + scol, &As[seg*512]);
      gll16(Bm + (size_t)(n0 + seg*16 + srow) * K + k0 + scol, &Bs[seg*512]);
    }
    __syncthreads();
    bf16x8 af[4], bfr[4];
    #pragma unroll
    for (int m = 0; m < 4; ++m)
      af[m] = *(const bf16x8*)&As[(wr*64 + m*16 + (l & 15))*32 + (l >> 4)*8];
    #pragma unroll
    for (int n = 0; n < 4; ++n)
      bfr[n] = *(const bf16x8*)&Bs[(wc*64 + n*16 + (l & 15))*32 + (l >> 4)*8];
    #pragma unroll
    for (int m = 0; m < 4; ++m)
      #pragma unroll
      for (int n = 0; n < 4; ++n)
        acc[m][n] = __builtin_amdgcn_mfma_f32_16x16x32_bf16(af[m], bfr[n], acc[m][n], 0, 0, 0);
  }

  const int g = l >> 4, c15 = l & 15;
  #pragma unroll
  for (int m = 0; m < 4; ++m) {
    #pragma unroll
    for (int n = 0; n < 4; ++n) {
      #pragma unroll
      for (int j = 0; j < 4; ++j) {
        const int row = m0 + wr*64 + m*16 + g*4 + j;
        const int col = n0 + wc*64 + n*16 + c15;
        const float v = acc[m][n][j] * scale;
        if (MODE == 0) {
          ((float*)Cout)[(size_t)row * D_MODEL + col] = v;
        } else {
          const int b = row >> 11, s = row & (SEQ-1);
          const int h = col >> 6, dh = col & (DHEAD-1);
          ((u16*)Cout)[(size_t)blockIdx.z * MTOT * D_MODEL
                       + ((size_t)(b*NHEADS + h) * SEQ + s) * DHEAD + dh] = f2bf(v);
        }
      }
    }
  }
}

// ---------------------------------------------------------------------------
// Causal flash attention, 8 warps x 32 q-rows (256-row superblock), 32x32x16
// MFMA, O^T form. grid = 512 (2 blocks/CU): block r -> bh = 8*(r&7)+((r>>3)&7)
// (XCD-pinned, 8 bh/XCD -> 4MB KV L2-fit); superblock sb = r<256 ? 7-(r>>6)
// : (r>>6)-4 -> blocks r and r+256 carry complementary loads (36 tiles/CU).
// Per kv-tile: S^T = mfma(K, Q^T) -> lane-local softmax (q = lane&31, T13
// defer-max) -> P^T B-frags via cvt_pk+permlane32_swap -> O^T += mfma(V^T,P^T).
// K via global_load_lds w/ pre-swizzled source; V^T scatter-staged.
// Chunk swizzle S(r) = (r&7)^(r>>3) on both. Epilogue transposes via LDS.
// ---------------------------------------------------------------------------
__launch_bounds__(512)
__global__ void attn5_k(const u16* __restrict__ Qb, const u16* __restrict__ Kb_,
                        const u16* __restrict__ Vb_, u16* __restrict__ Oa)
{
  const int tid = threadIdx.x;
  const int w = tid >> 6, l = tid & 63;
  const int q5 = l & 31, hi = l >> 5;
  const int r = blockIdx.x;
  const int bh = (r & 7) * 8 + ((r >> 3) & 7);
  const int p = r >> 6;                          // 0..7
  const int tq = (p < 4) ? (7 - p) : (p - 4);    // heavy first 256, light second
  const int b = bh >> 4, h = bh & 15;
  const size_t base = (size_t)bh * SEQ * DHEAD;
  const u16* Qg = Qb + base;
  const u16* Kg = Kb_ + base;
  const u16* Vg = Vb_ + base;

  // 32KB: K bufs [2][4096] | V bufs at +8192 [2][4096]; reused as Ot[8][2048]
  __shared__ __align__(16) u16 smem[16384];

  // V staging coords: thread loads V[row][kc*8..+7]
  const int kc = tid & 7, row = tid >> 3;       // row 0..63
  // K staging: wave w stages rows 8w..8w+7 (1KB via one gll16)
  const int kr8 = l >> 3;
  const int kkv = 8*w + kr8;
  const int kdc = (l & 7) ^ kr8 ^ w;            // pre-swizzled source d-chunk

  int vidx[8];
  #pragma unroll
  for (int e = 0; e < 8; ++e)
    vidx[e] = (8*kc + e)*64 + (((row >> 3) ^ kc ^ e) & 7)*8 + (row & 7);

  const int q0w = tq*256 + 32*w;
  const int ntk = (tq + 1) * 4;                 // block kv-tiles
  const int ntw = (q0w >> 6) + 1;               // this warp's compute tiles

  bf16x8 qf[4];
  #pragma unroll
  for (int s = 0; s < 4; ++s)
    qf[s] = *(const bf16x8*)(Qg + (size_t)(q0w + q5)*DHEAD + 16*s + 8*hi);

  f32x16 c0 = {}, c1 = {};                      // O^T accum (cols q = lane&31)
  float mrun = -1e30f, lrun = 0.f;

  // prologue: stage tile 0 -> buf 0
  {
    gll16(Kg + (size_t)kkv*DHEAD + kdc*8, smem + w*512);
    const u16x8 vr0 = *(const u16x8*)(Vg + (size_t)row*DHEAD + kc*8);
    #pragma unroll
    for (int e = 0; e < 8; ++e) smem[8192 + vidx[e]] = vr0[e];
  }
  __syncthreads();

  for (int t = 0; t < ntk; ++t) {
    const int cur = t & 1;
    const bool pf = (t + 1 < ntk);
    u16x8 vr;
    if (pf) {
      vr = *(const u16x8*)(Vg + (size_t)((t+1)*64 + row)*DHEAD + kc*8);
      gll16(Kg + (size_t)((t+1)*64 + kkv)*DHEAD + kdc*8,
            smem + (cur^1)*4096 + w*512);
    }

    if (t < ntw) {
      const u16* Kb = smem + cur*4096;
      const u16* Vv = smem + 8192 + cur*4096;

      // ---- S^T = K * Q^T ----
      f32x16 st[2] = {{}, {}};
      __builtin_amdgcn_s_setprio(1);
      #pragma unroll
      for (int kb = 0; kb < 2; ++kb) {
        #pragma unroll
        for (int s = 0; s < 4; ++s) {
          const int slot = ((2*s + hi) ^ (l & 7) ^ (4*kb) ^ (q5 >> 3)) & 7;
          const bf16x8 kf = *(const bf16x8*)(Kb + (32*kb + q5)*64 + slot*8);
          st[kb] = __builtin_amdgcn_mfma_f32_32x32x16_bf16(kf, qf[s], st[kb], 0, 0, 0);
        }
      }
      __builtin_amdgcn_s_setprio(0);

      // ---- causal mask (warp's diagonal tile only) ----
      if (t == ntw - 1) {
        const int kv0 = t*64;
        #pragma unroll
        for (int kb = 0; kb < 2; ++kb)
          #pragma unroll
          for (int rr = 0; rr < 16; ++rr) {
            const int kvg = kv0 + 32*kb + (rr & 3) + 8*(rr >> 2) + 4*hi;
            if (kvg > q0w + q5) st[kb][rr] = -1e30f;
          }
      }

      // ---- lane-local online softmax w/ T13 defer-max (q-row = q5) ----
      float mx = -1e30f;
      #pragma unroll
      for (int kb = 0; kb < 2; ++kb)
        #pragma unroll
        for (int rr = 0; rr < 16; ++rr) mx = fmaxf(mx, st[kb][rr]);
      mx = fmaxf(mx, __shfl_xor(mx, 32));
      float alpha = 1.0f;
      if (!__all(mx <= mrun + 8.0f)) {
        const float mnew = fmaxf(mrun, mx);
        alpha = __builtin_amdgcn_exp2f(mrun - mnew);
        mrun = mnew;
        #pragma unroll
        for (int rr = 0; rr < 16; ++rr) { c0[rr] *= alpha; c1[rr] *= alpha; }
      }
      float rs = 0.f;
      #pragma unroll
      for (int kb = 0; kb < 2; ++kb)
        #pragma unroll
        for (int rr = 0; rr < 16; ++rr) {
          const float pe = __builtin_amdgcn_exp2f(st[kb][rr] - mrun);
          st[kb][rr] = pe;
          rs += pe;
        }
      rs += __shfl_xor(rs, 32);
      lrun = lrun * alpha + rs;

      // ---- P^T -> B-frags: 16 cvt_pk + 8 permlane32_swap ----
      bf16x8 pb[4];
      #pragma unroll
      for (int kb = 0; kb < 2; ++kb) {
        u32 pw[8];
        #pragma unroll
        for (int i = 0; i < 8; ++i) {
          u32 t0;
          asm("v_cvt_pk_bf16_f32 %0, %1, %2"
              : "=v"(t0) : "v"(st[kb][2*i]), "v"(st[kb][2*i+1]));
          pw[i] = t0;
        }
        asm("v_permlane32_swap_b32 %0, %1" : "+v"(pw[0]), "+v"(pw[2]));
        asm("v_permlane32_swap_b32 %0, %1" : "+v"(pw[1]), "+v"(pw[3]));
        asm("v_permlane32_swap_b32 %0, %1" : "+v"(pw[4]), "+v"(pw[6]));
        asm("v_permlane32_swap_b32 %0, %1" : "+v"(pw[5]), "+v"(pw[7]));
        pb[2*kb]   = __builtin_bit_cast(bf16x8, u32x4{pw[0], pw[1], pw[2], pw[3]});
        pb[2*kb+1] = __builtin_bit_cast(bf16x8, u32x4{pw[4], pw[5], pw[6], pw[7]});
      }

      // ---- O^T += V^T * P^T ----
      __builtin_amdgcn_s_setprio(1);
      #pragma unroll
      for (int s = 0; s < 4; ++s) {
        {
          const int slot = ((2*s + hi) ^ (l & 7) ^ (q5 >> 3)) & 7;
          const bf16x8 vf = *(const bf16x8*)(Vv + q5*64 + slot*8);
          c0 = __builtin_amdgcn_mfma_f32_32x32x16_bf16(vf, pb[s], c0, 0, 0, 0);
        }
        {
          const int slot = ((2*s + hi) ^ (l & 7) ^ 4 ^ (q5 >> 3)) & 7;
          const bf16x8 vf = *(const bf16x8*)(Vv + (32 + q5)*64 + slot*8);
          c1 = __builtin_amdgcn_mfma_f32_32x32x16_bf16(vf, pb[s], c1, 0, 0, 0);
        }
      }
      __builtin_amdgcn_s_setprio(0);
    }

    if (pf) {
      u16* Vd = smem + 8192 + (cur^1)*4096;
      #pragma unroll
      for (int e = 0; e < 8; ++e) Vd[vidx[e]] = vr[e];
    }
    __syncthreads();
  }

  // ---- epilogue: normalize (lane-local), transpose via LDS, store ----
  const float linv = __builtin_amdgcn_rcpf(lrun);
  #pragma unroll
  for (int Ab = 0; Ab < 2; ++Ab)
    #pragma unroll
    for (int rr = 0; rr < 16; ++rr) {
      const int d = 32*Ab + (rr & 3) + 8*(rr >> 2) + 4*hi;
      smem[w*2048 + q5*64 + (((d >> 3) ^ (q5 & 7)) & 7)*8 + (d & 7)] =
          f2bf((Ab ? c1[rr] : c0[rr]) * linv);
    }
  __syncthreads();
  #pragma unroll
  for (int cc = 0; cc < 4; ++cc) {
    const int dchunk = 4*hi + cc;
    const u16x8 vv = *(const u16x8*)&smem[w*2048 + q5*64 + ((dchunk ^ (q5 & 7)) & 7)*8];
    *(u16x8*)(Oa + (size_t)(b*SEQ + q0w + q5)*D_MODEL + h*DHEAD + 32*hi + 8*cc) = vv;
  }
}

extern "C" void kernel_launch(void* const* d_in, const int* in_sizes, int n_in,
                              void* d_out, int out_size, void* d_ws, size_t ws_size,
                              hipStream_t stream) {
  const float* X  = (const float*)d_in[0];
  const float* Wq = (const float*)d_in[1];
  const float* Wk = (const float*)d_in[2];
  const float* Wv = (const float*)d_in[3];
  const float* Wo = (const float*)d_in[4];

  u16* xb  = (u16*)d_ws;
  u16* wqb = xb  + (size_t)MTOT*D_MODEL;
  u16* wkb = wqb + (size_t)D_MODEL*D_MODEL;
  u16* wvb = wkb + (size_t)D_MODEL*D_MODEL;
  u16* wob = wvb + (size_t)D_MODEL*D_MODEL;
  u16* qkv = wob + (size_t)D_MODEL*D_MODEL;   // [3][B*H][S][64]
  u16* att = qkv + (size_t)3*MTOT*D_MODEL;    // [8192][1024]

  const int nx4 = MTOT*D_MODEL/4;
  const int nw4 = D_MODEL*D_MODEL/4;
  cvtk<<<nx4/256, 256, 0, stream>>>((const float4*)X, (u16x4*)xb, nx4);
  dim3 gc(nw4/256, 4, 1);
  cvtk4<<<gc, 256, 0, stream>>>((const float4*)Wq, (const float4*)Wk,
                                (const float4*)Wv, (const float4*)Wo,
                                (u16x4*)wqb, nw4);

  dim3 g1(MTOT/128, D_MODEL/128, 3);
  gemm_bt_k<1><<<g1, 256, 0, stream>>>(xb, wqb, wkb, wvb, (void*)qkv);

  attn5_k<<<512, 512, 0, stream>>>(qkv, qkv + (size_t)MTOT*D_MODEL,
                                   qkv + (size_t)2*MTOT*D_MODEL, att);

  dim3 g3(MTOT/128, D_MODEL/128, 1);
  gemm_bt_k<0><<<g3, 256, 0, stream>>>(att, wob, nullptr, nullptr, d_out);
}

// Round 6
// 162.116 us; speedup vs baseline: 1.2396x; 1.1009x over previous
//
#include <hip/hip_runtime.h>
#include <stdint.h>

#define D_MODEL 1024
#define NHEADS  16
#define DHEAD   64
#define BATCH   4
#define SEQ     2048
#define MTOT    (BATCH*SEQ)

typedef unsigned short u16;
typedef uint32_t u32;
typedef __bf16 bf16x8 __attribute__((ext_vector_type(8)));
typedef float  f32x4  __attribute__((ext_vector_type(4)));
typedef float  f32x16 __attribute__((ext_vector_type(16)));
typedef u16    u16x8  __attribute__((ext_vector_type(8)));
typedef u16    u16x4  __attribute__((ext_vector_type(4)));
typedef u32    u32x4  __attribute__((ext_vector_type(4)));

__device__ __forceinline__ u16 f2bf(float f) {
  uint32_t u = __builtin_bit_cast(uint32_t, f);
  u += 0x7fff + ((u >> 16) & 1);   // RNE
  return (u16)(u >> 16);
}

__device__ __forceinline__ void gll16(const u16* g, u16* lds) {
  __builtin_amdgcn_global_load_lds(
      (__attribute__((address_space(1))) void*)(g),
      (__attribute__((address_space(3))) void*)(lds), 16, 0, 0);
}

// fp32 -> bf16 elementwise
__global__ void cvtk(const float4* __restrict__ in, u16x4* __restrict__ out, int n4) {
  const int i = blockIdx.x * blockDim.x + threadIdx.x;
  if (i < n4) {
    const float4 f = in[i];
    u16x4 h;
    h[0] = f2bf(f.x); h[1] = f2bf(f.y); h[2] = f2bf(f.z); h[3] = f2bf(f.w);
    out[i] = h;
  }
}

// 4 weight matrices in one launch (blockIdx.y selects source; outputs contiguous)
__global__ void cvtk4(const float4* __restrict__ a, const float4* __restrict__ b,
                      const float4* __restrict__ c, const float4* __restrict__ d,
                      u16x4* __restrict__ out, int n4) {
  const int i = blockIdx.x * blockDim.x + threadIdx.x;
  if (i >= n4) return;
  const float4* src = (blockIdx.y == 0) ? a : (blockIdx.y == 1) ? b
                    : (blockIdx.y == 2) ? c : d;
  const float4 f = src[i];
  u16x4 h;
  h[0] = f2bf(f.x); h[1] = f2bf(f.y); h[2] = f2bf(f.z); h[3] = f2bf(f.w);
  out[(size_t)blockIdx.y * n4 + i] = h;
}

// C = A (MxK, bf16) * B^T (B stored [N][K], bf16)
// MODE 0: fp32 store to Cout[M][D_MODEL]
// MODE 1: QKV: grid.z selects W; bf16 store permuted to [z][B][H][S][DHEAD]; z==0 scaled 0.125*log2e
template<int MODE>
__launch_bounds__(256)
__global__ void gemm_bt_k(const u16* __restrict__ A,
                          const u16* __restrict__ W0,
                          const u16* __restrict__ W1,
                          const u16* __restrict__ W2,
                          void* __restrict__ Cout)
{
  constexpr int K = D_MODEL;
  const int tid = threadIdx.x;
  const int l = tid & 63, w = tid >> 6;
  const int m0 = blockIdx.x * 128;
  const int n0 = blockIdx.y * 128;
  const u16* Bm = W0;
  float scale = 1.0f;
  if (MODE == 1) {
    const int z = blockIdx.z;
    Bm = (z == 0) ? W0 : ((z == 1) ? W1 : W2);
    scale = (z == 0) ? 0.125f * 1.44269504088896f : 1.0f;
  }

  __shared__ __align__(16) u16 As[128*32];
  __shared__ __align__(16) u16 Bs[128*32];

  f32x4 acc[4][4];
  #pragma unroll
  for (int i = 0; i < 4; ++i)
    #pragma unroll
    for (int j = 0; j < 4; ++j)
      acc[i][j] = f32x4{0.f, 0.f, 0.f, 0.f};

  const int wr = w >> 1, wc = w & 1;
  const int srow = l >> 2;
  const int scol = (l & 3) * 8;

  for (int k0 = 0; k0 < K; k0 += 32) {
    __syncthreads();
    #pragma unroll
    for (int j = 0; j < 2; ++j) {
      const int seg = w * 2 + j;
      gll16(A  + (size_t)(m0 + seg*16 + srow) * K + k0 + scol, &As[seg*512]);
      gll16(Bm + (size_t)(n0 + seg*16 + srow) * K + k0 + scol, &Bs[seg*512]);
    }
    __syncthreads();
    bf16x8 af[4], bfr[4];
    #pragma unroll
    for (int m = 0; m < 4; ++m)
      af[m] = *(const bf16x8*)&As[(wr*64 + m*16 + (l & 15))*32 + (l >> 4)*8];
    #pragma unroll
    for (int n = 0; n < 4; ++n)
      bfr[n] = *(const bf16x8*)&Bs[(wc*64 + n*16 + (l & 15))*32 + (l >> 4)*8];
    #pragma unroll
    for (int m = 0; m < 4; ++m)
      #pragma unroll
      for (int n = 0; n < 4; ++n)
        acc[m][n] = __builtin_amdgcn_mfma_f32_16x16x32_bf16(af[m], bfr[n], acc[m][n], 0, 0, 0);
  }

  const int g = l >> 4, c15 = l & 15;
  #pragma unroll
  for (int m = 0; m < 4; ++m) {
    #pragma unroll
    for (int n = 0; n < 4; ++n) {
      #pragma unroll
      for (int j = 0; j < 4; ++j) {
        const int row = m0 + wr*64 + m*16 + g*4 + j;
        const int col = n0 + wc*64 + n*16 + c15;
        const float v = acc[m][n][j] * scale;
        if (MODE == 0) {
          ((float*)Cout)[(size_t)row * D_MODEL + col] = v;
        } else {
          const int b = row >> 11, s = row & (SEQ-1);
          const int h = col >> 6, dh = col & (DHEAD-1);
          ((u16*)Cout)[(size_t)blockIdx.z * MTOT * D_MODEL
                       + ((size_t)(b*NHEADS + h) * SEQ + s) * DHEAD + dh] = f2bf(v);
        }
      }
    }
  }
}

// ---------------------------------------------------------------------------
// Causal flash attention, 8 warps x 32 q-rows (256-row superblock), KVBLK=128
// (two attn3-identical 64-kv sub-tiles per buffer), 32x32x16 MFMA, O^T form.
// grid = 256 (1 block/CU): block r -> bh = 8*(r&7)+((r>>3)&7) (XCD-pinned),
// pairi = r>>6; halves tq in {pairi, 7-pairi} -> constant 18 kv-tiles/block.
// Per kv-tile: S^T = mfma(K, Q^T) -> lane-local softmax (q = lane&31, T13
// defer-max) -> P^T B-frags via cvt_pk+permlane32_swap -> O^T += mfma(V^T,P^T).
// K via global_load_lds w/ pre-swizzled source; V^T scatter-staged as
// paired-row u32 writes. Chunk swizzle S(r)=(r&7)^(r>>3) per 64-kv sub-tile.
// ---------------------------------------------------------------------------
__launch_bounds__(512, 2)
__global__ void attn6_k(const u16* __restrict__ Qb, const u16* __restrict__ Kb_,
                        const u16* __restrict__ Vb_, u16* __restrict__ Oa)
{
  const int tid = threadIdx.x;
  const int w = tid >> 6, l = tid & 63;
  const int q5 = l & 31, hi = l >> 5;
  const int r = blockIdx.x;
  const int bh = (r & 7) * 8 + ((r >> 3) & 7);
  const int pairi = r >> 6;                     // 0..3
  const int b = bh >> 4, h = bh & 15;
  const size_t base = (size_t)bh * SEQ * DHEAD;
  const u16* Qg = Qb + base;
  const u16* Kg = Kb_ + base;
  const u16* Vg = Vb_ + base;

  // 64KB: K bufs [2][8192] u16 | V bufs at u16-ofs 16384 [2][8192]
  // epilogue reuses smem[0..16383] as Ot[8][2048]
  __shared__ __align__(16) u16 smem[32768];

  // V staging: thread handles kv rows {2*rp, 2*rp+1} (rp 0..63), d-chunk kc
  const int kc = tid & 7, rp = tid >> 3;
  const int vsub = rp >> 5;                     // 64-kv sub-tile
  const int rp5 = rp & 31;
  int vIdx32[8];
  #pragma unroll
  for (int e = 0; e < 8; ++e)
    vIdx32[e] = vsub*2048 + (8*kc + e)*32 + ((((rp5 >> 2) ^ kc ^ e) & 7) << 2) + (rp5 & 3);

  // K staging: per sub-tile h2, wave w stages rows 8w..8w+7 (one gll16 each)
  const int kr8 = l >> 3;
  const int kkv = 8*w + kr8;                    // row within sub-tile
  const int kdc = (l & 7) ^ kr8 ^ w;            // pre-swizzled source d-chunk

  for (int half = 0; half < 2; ++half) {
    const int tq = half ? (7 - pairi) : pairi;
    const int q0w = tq*256 + 32*w;
    const int ntk = (tq + 1) * 2;               // 128-kv tiles for block
    const int ntw = (q0w >> 7) + 1;             // this warp's compute tiles

    bf16x8 qf[4];
    #pragma unroll
    for (int s = 0; s < 4; ++s)
      qf[s] = *(const bf16x8*)(Qg + (size_t)(q0w + q5)*DHEAD + 16*s + 8*hi);

    f32x16 c0 = {}, c1 = {};                    // O^T accum (cols q = lane&31)
    float mrun = -1e30f, lrun = 0.f;

    // prologue: stage tile 0 -> buf 0
    {
      #pragma unroll
      for (int h2 = 0; h2 < 2; ++h2)
        gll16(Kg + (size_t)(64*h2 + kkv)*DHEAD + kdc*8, smem + h2*4096 + w*512);
      const u16x8 v0 = *(const u16x8*)(Vg + (size_t)(2*rp)*DHEAD + kc*8);
      const u16x8 v1 = *(const u16x8*)(Vg + (size_t)(2*rp + 1)*DHEAD + kc*8);
      u32* Vd = (u32*)(smem + 16384);
      #pragma unroll
      for (int e = 0; e < 8; ++e)
        Vd[vIdx32[e]] = (u32)v0[e] | ((u32)v1[e] << 16);
    }
    __syncthreads();

    for (int t = 0; t < ntk; ++t) {
      const int cur = t & 1;
      const bool pf = (t + 1 < ntk);
      u16x8 v0, v1;
      if (pf) {
        const int kv1 = (t + 1) * 128;
        v0 = *(const u16x8*)(Vg + (size_t)(kv1 + 2*rp)*DHEAD + kc*8);
        v1 = *(const u16x8*)(Vg + (size_t)(kv1 + 2*rp + 1)*DHEAD + kc*8);
        #pragma unroll
        for (int h2 = 0; h2 < 2; ++h2)
          gll16(Kg + (size_t)(kv1 + 64*h2 + kkv)*DHEAD + kdc*8,
                smem + (cur^1)*8192 + h2*4096 + w*512);
      }

      if (t < ntw) {
        const u16* Kb = smem + cur*8192;
        const u16* Vv = smem + 16384 + cur*8192;

        // ---- S^T = K * Q^T  (4 blocks of 32 kv) ----
        f32x16 st[4] = {{}, {}, {}, {}};
        __builtin_amdgcn_s_setprio(1);
        #pragma unroll
        for (int kbg = 0; kbg < 4; ++kbg) {
          #pragma unroll
          for (int s = 0; s < 4; ++s) {
            const int slot = ((2*s + hi) ^ (l & 7) ^ ((4*(kbg & 1)) & 7) ^ (q5 >> 3)) & 7;
            const bf16x8 kf = *(const bf16x8*)(Kb + (kbg >> 1)*4096
                                               + ((kbg & 1)*32 + q5)*64 + slot*8);
            st[kbg] = __builtin_amdgcn_mfma_f32_32x32x16_bf16(kf, qf[s], st[kbg], 0, 0, 0);
          }
        }
        __builtin_amdgcn_s_setprio(0);

        // ---- causal mask (warp's diagonal tile only) ----
        if (t == ntw - 1) {
          const int kv0 = t * 128;
          #pragma unroll
          for (int kbg = 0; kbg < 4; ++kbg)
            #pragma unroll
            for (int rr = 0; rr < 16; ++rr) {
              const int kvg = kv0 + 32*kbg + (rr & 3) + 8*(rr >> 2) + 4*hi;
              if (kvg > q0w + q5) st[kbg][rr] = -1e30f;
            }
        }

        // ---- lane-local online softmax w/ T13 defer-max (q-row = q5) ----
        float mx = -1e30f;
        #pragma unroll
        for (int kbg = 0; kbg < 4; ++kbg)
          #pragma unroll
          for (int rr = 0; rr < 16; ++rr) mx = fmaxf(mx, st[kbg][rr]);
        mx = fmaxf(mx, __shfl_xor(mx, 32));
        float alpha = 1.0f;
        if (!__all(mx <= mrun + 8.0f)) {
          const float mnew = fmaxf(mrun, mx);
          alpha = __builtin_amdgcn_exp2f(mrun - mnew);
          mrun = mnew;
          #pragma unroll
          for (int rr = 0; rr < 16; ++rr) { c0[rr] *= alpha; c1[rr] *= alpha; }
        }
        float rs = 0.f;
        #pragma unroll
        for (int kbg = 0; kbg < 4; ++kbg)
          #pragma unroll
          for (int rr = 0; rr < 16; ++rr) {
            const float pe = __builtin_amdgcn_exp2f(st[kbg][rr] - mrun);
            st[kbg][rr] = pe;
            rs += pe;
          }
        rs += __shfl_xor(rs, 32);
        lrun = lrun * alpha + rs;

        // ---- P^T -> B-frags: 32 cvt_pk + 16 permlane32_swap ----
        bf16x8 pb[8];
        #pragma unroll
        for (int kbg = 0; kbg < 4; ++kbg) {
          u32 pw[8];
          #pragma unroll
          for (int i = 0; i < 8; ++i) {
            u32 t0;
            asm("v_cvt_pk_bf16_f32 %0, %1, %2"
                : "=v"(t0) : "v"(st[kbg][2*i]), "v"(st[kbg][2*i+1]));
            pw[i] = t0;
          }
          asm("v_permlane32_swap_b32 %0, %1" : "+v"(pw[0]), "+v"(pw[2]));
          asm("v_permlane32_swap_b32 %0, %1" : "+v"(pw[1]), "+v"(pw[3]));
          asm("v_permlane32_swap_b32 %0, %1" : "+v"(pw[4]), "+v"(pw[6]));
          asm("v_permlane32_swap_b32 %0, %1" : "+v"(pw[5]), "+v"(pw[7]));
          pb[2*kbg]   = __builtin_bit_cast(bf16x8, u32x4{pw[0], pw[1], pw[2], pw[3]});
          pb[2*kbg+1] = __builtin_bit_cast(bf16x8, u32x4{pw[4], pw[5], pw[6], pw[7]});
        }

        // ---- O^T += V^T * P^T  (per 64-kv sub-tile) ----
        __builtin_amdgcn_s_setprio(1);
        #pragma unroll
        for (int h2 = 0; h2 < 2; ++h2) {
          #pragma unroll
          for (int s = 0; s < 4; ++s) {
            {
              const int slot = ((2*s + hi) ^ (l & 7) ^ (q5 >> 3)) & 7;
              const bf16x8 vf = *(const bf16x8*)(Vv + h2*4096 + q5*64 + slot*8);
              c0 = __builtin_amdgcn_mfma_f32_32x32x16_bf16(vf, pb[4*h2 + s], c0, 0, 0, 0);
            }
            {
              const int slot = ((2*s + hi) ^ (l & 7) ^ 4 ^ (q5 >> 3)) & 7;
              const bf16x8 vf = *(const bf16x8*)(Vv + h2*4096 + (32 + q5)*64 + slot*8);
              c1 = __builtin_amdgcn_mfma_f32_32x32x16_bf16(vf, pb[4*h2 + s], c1, 0, 0, 0);
            }
          }
        }
        __builtin_amdgcn_s_setprio(0);
      }

      if (pf) {
        u32* Vd = (u32*)(smem + 16384) + (cur^1)*4096;
        #pragma unroll
        for (int e = 0; e < 8; ++e)
          Vd[vIdx32[e]] = (u32)v0[e] | ((u32)v1[e] << 16);
      }
      __syncthreads();
    }

    // ---- epilogue: normalize (lane-local), transpose via LDS, store ----
    const float linv = __builtin_amdgcn_rcpf(lrun);
    #pragma unroll
    for (int Ab = 0; Ab < 2; ++Ab)
      #pragma unroll
      for (int rr = 0; rr < 16; ++rr) {
        const int d = 32*Ab + (rr & 3) + 8*(rr >> 2) + 4*hi;
        smem[w*2048 + q5*64 + (((d >> 3) ^ (q5 & 7)) & 7)*8 + (d & 7)] =
            f2bf((Ab ? c1[rr] : c0[rr]) * linv);
      }
    __syncthreads();
    #pragma unroll
    for (int cc = 0; cc < 4; ++cc) {
      const int dchunk = 4*hi + cc;
      const u16x8 vv = *(const u16x8*)&smem[w*2048 + q5*64 + ((dchunk ^ (q5 & 7)) & 7)*8];
      *(u16x8*)(Oa + (size_t)(b*SEQ + q0w + q5)*D_MODEL + h*DHEAD + 32*hi + 8*cc) = vv;
    }
    __syncthreads();
  }
}

extern "C" void kernel_launch(void* const* d_in, const int* in_sizes, int n_in,
                              void* d_out, int out_size, void* d_ws, size_t ws_size,
                              hipStream_t stream) {
  const float* X  = (const float*)d_in[0];
  const float* Wq = (const float*)d_in[1];
  const float* Wk = (const float*)d_in[2];
  const float* Wv = (const float*)d_in[3];
  const float* Wo = (const float*)d_in[4];

  u16* xb  = (u16*)d_ws;
  u16* wqb = xb  + (size_t)MTOT*D_MODEL;
  u16* wkb = wqb + (size_t)D_MODEL*D_MODEL;
  u16* wvb = wkb + (size_t)D_MODEL*D_MODEL;
  u16* wob = wvb + (size_t)D_MODEL*D_MODEL;
  u16* qkv = wob + (size_t)D_MODEL*D_MODEL;   // [3][B*H][S][64]
  u16* att = qkv + (size_t)3*MTOT*D_MODEL;    // [8192][1024]

  const int nx4 = MTOT*D_MODEL/4;
  const int nw4 = D_MODEL*D_MODEL/4;
  cvtk<<<nx4/256, 256, 0, stream>>>((const float4*)X, (u16x4*)xb, nx4);
  dim3 gc(nw4/256, 4, 1);
  cvtk4<<<gc, 256, 0, stream>>>((const float4*)Wq, (const float4*)Wk,
                                (const float4*)Wv, (const float4*)Wo,
                                (u16x4*)wqb, nw4);

  dim3 g1(MTOT/128, D_MODEL/128, 3);
  gemm_bt_k<1><<<g1, 256, 0, stream>>>(xb, wqb, wkb, wvb, (void*)qkv);

  attn6_k<<<256, 512, 0, stream>>>(qkv, qkv + (size_t)MTOT*D_MODEL,
                                   qkv + (size_t)2*MTOT*D_MODEL, att);

  dim3 g3(MTOT/128, D_MODEL/128, 1);
  gemm_bt_k<0><<<g3, 256, 0, stream>>>(att, wob, nullptr, nullptr, d_out);
}